// Round 1
// baseline (13418.861 us; speedup 1.0000x reference)
//
#include <hip/hip_runtime.h>

#define NB 16

__device__ __forceinline__ float sig_(float x) { return 1.0f / (1.0f + __expf(-x)); }
__device__ __forceinline__ float th_(float x)  { return 1.0f - 2.0f / (__expf(2.0f * x) + 1.0f); }

// ---------------------------------------------------------------------------
// Fused NT GEMM: acc[m][g*256+j] = sum_k A[m][k] * Wt[g*256+j][k]
// grid (ceil(M/64), 4), block 256. Tile: 64 m x 64 h-idx (x4 gates = 256 cols).
// mode 0/2: Cout = acc + bias      (emb2 build / gatesB build)
// mode 1:   LSTM token step t: gates = acc + emb2[tok[m][t]]; c,h update,
//           conditional instr_feats write.
// ---------------------------------------------------------------------------
__global__ __launch_bounds__(256, 2)
void gemm_fused(const float* __restrict__ A, const float* __restrict__ Wt,
                const float* __restrict__ bias, float* __restrict__ Cout,
                int M, int mode,
                const int* __restrict__ tok, int t, const float* __restrict__ emb2,
                const int* __restrict__ lengths, float* __restrict__ cbuf,
                float* __restrict__ hout, float* __restrict__ feats)
{
    __shared__ float a_lds[32][64];       // [k][m]
    __shared__ float b_lds[4][32][64];    // [gate][k][r]
    const int tid = threadIdx.x;
    const int tn = tid & 15;              // -> 4 m rows
    const int th = tid >> 4;              // -> 4 h cols
    const int m0 = blockIdx.x * 64;
    const int j0 = blockIdx.y * 64;

    float acc[4][4][4];                   // [gate][hi][ni]
    #pragma unroll
    for (int g = 0; g < 4; ++g)
        #pragma unroll
        for (int x = 0; x < 4; ++x)
            #pragma unroll
            for (int y = 0; y < 4; ++y) acc[g][x][y] = 0.f;

    float4 abuf[2], bbuf[8];
    auto load_t = [&](int k0) {
        #pragma unroll
        for (int p = 0; p < 2; ++p) {
            int idx = tid + p * 256, ml = idx >> 3, k4 = idx & 7;
            int row = m0 + ml;
            abuf[p] = (row < M) ? *(const float4*)&A[row * 256 + k0 + k4 * 4]
                                : make_float4(0.f, 0.f, 0.f, 0.f);
        }
        #pragma unroll
        for (int p = 0; p < 8; ++p) {
            int idx = tid + p * 256;
            int g = idx >> 9, rem = idx & 511, r = rem >> 3, k4 = rem & 7;
            bbuf[p] = *(const float4*)&Wt[(g * 256 + j0 + r) * 256 + k0 + k4 * 4];
        }
    };
    auto store_t = [&]() {
        #pragma unroll
        for (int p = 0; p < 2; ++p) {
            int idx = tid + p * 256, ml = idx >> 3, k4 = idx & 7;
            a_lds[k4 * 4 + 0][ml] = abuf[p].x;
            a_lds[k4 * 4 + 1][ml] = abuf[p].y;
            a_lds[k4 * 4 + 2][ml] = abuf[p].z;
            a_lds[k4 * 4 + 3][ml] = abuf[p].w;
        }
        #pragma unroll
        for (int p = 0; p < 8; ++p) {
            int idx = tid + p * 256;
            int g = idx >> 9, rem = idx & 511, r = rem >> 3, k4 = rem & 7;
            b_lds[g][k4 * 4 + 0][r] = bbuf[p].x;
            b_lds[g][k4 * 4 + 1][r] = bbuf[p].y;
            b_lds[g][k4 * 4 + 2][r] = bbuf[p].z;
            b_lds[g][k4 * 4 + 3][r] = bbuf[p].w;
        }
    };

    load_t(0); store_t(); __syncthreads();
    for (int c = 0; c < 8; ++c) {
        if (c < 7) load_t((c + 1) * 32);  // reg double-buffer: hide global latency
        #pragma unroll 8
        for (int k = 0; k < 32; ++k) {
            float4 a4 = *(const float4*)&a_lds[k][tn * 4];
            float av[4] = {a4.x, a4.y, a4.z, a4.w};
            #pragma unroll
            for (int g = 0; g < 4; ++g) {
                float4 b4 = *(const float4*)&b_lds[g][k][th * 4];
                float bv[4] = {b4.x, b4.y, b4.z, b4.w};
                #pragma unroll
                for (int hi = 0; hi < 4; ++hi)
                    #pragma unroll
                    for (int ni = 0; ni < 4; ++ni)
                        acc[g][hi][ni] += bv[hi] * av[ni];
            }
        }
        __syncthreads();
        if (c < 7) { store_t(); __syncthreads(); }
    }

    const int colb = j0 + th * 4;
    if (mode != 1) {
        float4 bs[4];
        #pragma unroll
        for (int g = 0; g < 4; ++g) bs[g] = *(const float4*)&bias[g * 256 + colb];
        #pragma unroll
        for (int ni = 0; ni < 4; ++ni) {
            int row = m0 + tn * 4 + ni;
            if (row < M) {
                #pragma unroll
                for (int g = 0; g < 4; ++g) {
                    float4 o;
                    o.x = acc[g][0][ni] + bs[g].x;
                    o.y = acc[g][1][ni] + bs[g].y;
                    o.z = acc[g][2][ni] + bs[g].z;
                    o.w = acc[g][3][ni] + bs[g].w;
                    *(float4*)&Cout[row * 1024 + g * 256 + colb] = o;
                }
            }
        }
    } else {
        #pragma unroll
        for (int ni = 0; ni < 4; ++ni) {
            int n = m0 + tn * 4 + ni;
            int v = tok[n * 16 + t];
            const float* e = emb2 + v * 1024 + colb;
            float4 e0 = *(const float4*)(e);
            float4 e1 = *(const float4*)(e + 256);
            float4 e2 = *(const float4*)(e + 512);
            float4 e3 = *(const float4*)(e + 768);
            float4 co = *(const float4*)&cbuf[n * 256 + colb];
            float eg[4][4] = {{e0.x, e0.y, e0.z, e0.w}, {e1.x, e1.y, e1.z, e1.w},
                              {e2.x, e2.y, e2.z, e2.w}, {e3.x, e3.y, e3.z, e3.w}};
            float cold[4] = {co.x, co.y, co.z, co.w};
            float cn[4], hn[4];
            #pragma unroll
            for (int hi = 0; hi < 4; ++hi) {
                float ig = acc[0][hi][ni] + eg[0][hi];
                float fg = acc[1][hi][ni] + eg[1][hi];
                float gg = acc[2][hi][ni] + eg[2][hi];
                float og = acc[3][hi][ni] + eg[3][hi];
                float cc = sig_(fg) * cold[hi] + sig_(ig) * th_(gg);
                cn[hi] = cc;
                hn[hi] = sig_(og) * th_(cc);
            }
            float4 c4 = make_float4(cn[0], cn[1], cn[2], cn[3]);
            float4 h4 = make_float4(hn[0], hn[1], hn[2], hn[3]);
            *(float4*)&cbuf[n * 256 + colb] = c4;
            *(float4*)&hout[n * 256 + colb] = h4;
            if (lengths[n] == t + 1) *(float4*)&feats[n * 256 + colb] = h4;
        }
    }
}

// ---------------------------------------------------------------------------
// Token-LSTM step 0 (h0 = c0 = 0 -> pure pointwise from emb2 gather)
// ---------------------------------------------------------------------------
__global__ __launch_bounds__(256)
void step0_kernel(const int* __restrict__ tok, const int* __restrict__ lengths,
                  const float* __restrict__ emb2, float* __restrict__ cbuf,
                  float* __restrict__ h0, float* __restrict__ feats)
{
    int n = blockIdx.x, j = threadIdx.x;
    int v = tok[n * 16];
    const float* e = emb2 + v * 1024;
    float ig = e[j], gg = e[512 + j], og = e[768 + j];
    float c = sig_(ig) * th_(gg);          // f-gate * c0 drops (c0 = 0)
    float h = sig_(og) * th_(c);
    cbuf[n * 256 + j] = c;
    h0[n * 256 + j] = h;
    if (lengths[n] == 1) feats[n * 256 + j] = h;
}

// ---------------------------------------------------------------------------
// Instruction-LSTM scan: 4096 sequential steps, batch 1, H=256.
// 16 persistent blocks; block b owns h-indices [b*16, b*16+16) and its 64
// W_hh rows (64 KB LDS). Per-step h exchange via agent-scope atomics +
// padded per-block flags (message passing: release flag after h stores,
// acquire flag before h loads; h double-buffered).
// ---------------------------------------------------------------------------
__global__ __launch_bounds__(256, 1)
void scan_kernel(const float* __restrict__ gatesB, const float* __restrict__ Whh,
                 const float* __restrict__ linW, const float* __restrict__ linb,
                 float* __restrict__ hx, int* __restrict__ flags,
                 float* __restrict__ out)
{
    const int b = blockIdx.x;
    const int tid = threadIdx.x;
    const int r = tid >> 2;               // 0..63: gate-row (g = r>>4, i = r&15)
    const int q = tid & 3;                // k-quarter
    __shared__ float w_lds[64][260];      // +4 pad: breaks power-of-2 bank stride
    __shared__ float h_lds[256];
    __shared__ float gate_lds[64];
    __shared__ float c_lds[16];
    __shared__ float red_lds[4];

    #pragma unroll
    for (int p = 0; p < 16; ++p) {        // stage 64 W rows x 256 k
        int idx = tid + p * 256;
        int rr = idx >> 6, k4 = idx & 63;
        int gg = rr >> 4, ii = rr & 15;
        float4 v = *(const float4*)&Whh[(gg * 256 + b * 16 + ii) * 256 + k4 * 4];
        *(float4*)&w_lds[rr][k4 * 4] = v;
    }
    if (tid < 16) c_lds[tid] = 0.f;
    h_lds[tid] = 0.f;                     // h_0 = 0
    __syncthreads();

    for (int s = 0; s < 4096; ++s) {
        // prefetch this step's input-gate row (independent of h -> overlaps)
        float bg0 = 0.f, bg1 = 0.f, bg2 = 0.f, bg3 = 0.f;
        if (tid < 16) {
            const float* gp = gatesB + s * 1024 + b * 16 + tid;
            bg0 = gp[0]; bg1 = gp[256]; bg2 = gp[512]; bg3 = gp[768];
        }
        // matvec: thread (r,q) covers k = q*64 .. q*64+63
        float4 ac = make_float4(0.f, 0.f, 0.f, 0.f);
        #pragma unroll
        for (int kk = 0; kk < 16; ++kk) {
            float4 w4 = *(const float4*)&w_lds[r][q * 64 + kk * 4];
            float4 h4 = *(const float4*)&h_lds[q * 64 + kk * 4];
            ac.x += w4.x * h4.x; ac.y += w4.y * h4.y;
            ac.z += w4.z * h4.z; ac.w += w4.w * h4.w;
        }
        float sum = (ac.x + ac.y) + (ac.z + ac.w);
        sum += __shfl_xor(sum, 1);
        sum += __shfl_xor(sum, 2);
        if (q == 0) gate_lds[r] = sum;
        __syncthreads();
        if (tid < 16) {
            float ig = gate_lds[tid]      + bg0;
            float fg = gate_lds[16 + tid] + bg1;
            float gg = gate_lds[32 + tid] + bg2;
            float og = gate_lds[48 + tid] + bg3;
            float cc = sig_(fg) * c_lds[tid] + sig_(ig) * th_(gg);
            c_lds[tid] = cc;
            float hh = sig_(og) * th_(cc);
            __hip_atomic_store(&hx[((s + 1) & 1) * 256 + b * 16 + tid], hh,
                               __ATOMIC_RELAXED, __HIP_MEMORY_SCOPE_AGENT);
        }
        __syncthreads();                  // drains vmem before barrier exit
        if (tid == 0) {
            __threadfence();              // publish h stores device-wide
            __hip_atomic_store(&flags[((s + 1) * NB + b) * 16], 1,
                               __ATOMIC_RELEASE, __HIP_MEMORY_SCOPE_AGENT);
        }
        if (tid < NB) {
            while (__hip_atomic_load(&flags[((s + 1) * NB + tid) * 16],
                                     __ATOMIC_ACQUIRE, __HIP_MEMORY_SCOPE_AGENT) == 0) {
                __builtin_amdgcn_s_sleep(1);
            }
        }
        __syncthreads();
        h_lds[tid] = __hip_atomic_load(&hx[((s + 1) & 1) * 256 + tid],
                                       __ATOMIC_RELAXED, __HIP_MEMORY_SCOPE_AGENT);
        __syncthreads();
    }

    if (b == 0) {                         // out = h_T . lin_W + lin_b
        float p = h_lds[tid] * linW[tid];
        #pragma unroll
        for (int off = 1; off < 64; off <<= 1) p += __shfl_xor(p, off);
        if ((tid & 63) == 0) red_lds[tid >> 6] = p;
        __syncthreads();
        if (tid == 0) out[0] = red_lds[0] + red_lds[1] + red_lds[2] + red_lds[3] + linb[0];
    }
}

extern "C" void kernel_launch(void* const* d_in, const int* in_sizes, int n_in,
                              void* d_out, int out_size, void* d_ws, size_t ws_size,
                              hipStream_t stream)
{
    const int*   tok  = (const int*)d_in[0];
    const int*   len  = (const int*)d_in[1];
    const float* emb  = (const float*)d_in[2];
    const float* tWih = (const float*)d_in[3];
    const float* tWhh = (const float*)d_in[4];
    const float* tb   = (const float*)d_in[5];
    const float* iWih = (const float*)d_in[6];
    const float* iWhh = (const float*)d_in[7];
    const float* ib   = (const float*)d_in[8];
    const float* lW   = (const float*)d_in[9];
    const float* lb   = (const float*)d_in[10];
    float* out = (float*)d_out;

    // workspace layout (floats): ~44 MiB total
    float* emb2   = (float*)d_ws;           // [2000][1024]
    float* hbuf0  = emb2  + 2048000;        // [4096][256] ping
    float* hbuf1  = hbuf0 + 1048576;        // [4096][256] pong
    float* cbuf   = hbuf1 + 1048576;        // [4096][256]
    float* feats  = cbuf  + 1048576;        // [4096][256]
    float* gatesB = feats + 1048576;        // [4096][1024]
    float* hx     = gatesB + 4194304;       // [2][256]
    int*   flags  = (int*)(hx + 512);       // [4097][16] flags, 64B-padded

    hipMemsetAsync(flags, 0, (size_t)1048832 * sizeof(int), stream);

    // emb2 = emb @ tok_W_ih^T + tok_b  (V=2000 rows)
    gemm_fused<<<dim3(32, 4), 256, 0, stream>>>(emb, tWih, tb, emb2, 2000, 0,
                                                nullptr, 0, nullptr, nullptr,
                                                nullptr, nullptr, nullptr);
    // token LSTM step 0 (pointwise)
    step0_kernel<<<4096, 256, 0, stream>>>(tok, len, emb2, cbuf, hbuf0, feats);
    // token LSTM steps 1..15 (fused GEMM + gather + activations)
    for (int t = 1; t < 16; ++t) {
        float* hprev = (t & 1) ? hbuf0 : hbuf1;
        float* hcur  = (t & 1) ? hbuf1 : hbuf0;
        gemm_fused<<<dim3(64, 4), 256, 0, stream>>>(hprev, tWhh, nullptr, nullptr,
                                                    4096, 1, tok, t, emb2, len,
                                                    cbuf, hcur, feats);
    }
    // gatesB = instr_feats @ ins_W_ih^T + ins_b
    gemm_fused<<<dim3(64, 4), 256, 0, stream>>>(feats, iWih, ib, gatesB, 4096, 2,
                                                nullptr, 0, nullptr, nullptr,
                                                nullptr, nullptr, nullptr);
    // 4096-step sequential instruction LSTM + final linear
    scan_kernel<<<NB, 256, 0, stream>>>(gatesB, iWhh, lW, lb, hx, flags, out);
}

// Round 2
// 8035.955 us; speedup vs baseline: 1.6699x; 1.6699x over previous
//
#include <hip/hip_runtime.h>

#define NB 16

__device__ __forceinline__ float sig_(float x) { return 1.0f / (1.0f + __expf(-x)); }
__device__ __forceinline__ float th_(float x)  { return 1.0f - 2.0f / (__expf(2.0f * x) + 1.0f); }

// ---------------------------------------------------------------------------
// Fused NT GEMM: acc[m][g*256+j] = sum_k A[m][k] * Wt[g*256+j][k]
// grid (ceil(M/64), 4), block 256. Tile: 64 m x 64 h-idx (x4 gates = 256 cols).
// mode 0/2: Cout = acc + bias      (emb2 build / gatesB build)
// mode 1:   LSTM token step t: gates = acc + emb2[tok[m][t]]; c,h update,
//           conditional instr_feats write.
// ---------------------------------------------------------------------------
__global__ __launch_bounds__(256, 2)
void gemm_fused(const float* __restrict__ A, const float* __restrict__ Wt,
                const float* __restrict__ bias, float* __restrict__ Cout,
                int M, int mode,
                const int* __restrict__ tok, int t, const float* __restrict__ emb2,
                const int* __restrict__ lengths, float* __restrict__ cbuf,
                float* __restrict__ hout, float* __restrict__ feats)
{
    __shared__ float a_lds[32][64];       // [k][m]
    __shared__ float b_lds[4][32][64];    // [gate][k][r]
    const int tid = threadIdx.x;
    const int tn = tid & 15;              // -> 4 m rows
    const int th = tid >> 4;              // -> 4 h cols
    const int m0 = blockIdx.x * 64;
    const int j0 = blockIdx.y * 64;

    float acc[4][4][4];                   // [gate][hi][ni]
    #pragma unroll
    for (int g = 0; g < 4; ++g)
        #pragma unroll
        for (int x = 0; x < 4; ++x)
            #pragma unroll
            for (int y = 0; y < 4; ++y) acc[g][x][y] = 0.f;

    float4 abuf[2], bbuf[8];
    auto load_t = [&](int k0) {
        #pragma unroll
        for (int p = 0; p < 2; ++p) {
            int idx = tid + p * 256, ml = idx >> 3, k4 = idx & 7;
            int row = m0 + ml;
            abuf[p] = (row < M) ? *(const float4*)&A[row * 256 + k0 + k4 * 4]
                                : make_float4(0.f, 0.f, 0.f, 0.f);
        }
        #pragma unroll
        for (int p = 0; p < 8; ++p) {
            int idx = tid + p * 256;
            int g = idx >> 9, rem = idx & 511, r = rem >> 3, k4 = rem & 7;
            bbuf[p] = *(const float4*)&Wt[(g * 256 + j0 + r) * 256 + k0 + k4 * 4];
        }
    };
    auto store_t = [&]() {
        #pragma unroll
        for (int p = 0; p < 2; ++p) {
            int idx = tid + p * 256, ml = idx >> 3, k4 = idx & 7;
            a_lds[k4 * 4 + 0][ml] = abuf[p].x;
            a_lds[k4 * 4 + 1][ml] = abuf[p].y;
            a_lds[k4 * 4 + 2][ml] = abuf[p].z;
            a_lds[k4 * 4 + 3][ml] = abuf[p].w;
        }
        #pragma unroll
        for (int p = 0; p < 8; ++p) {
            int idx = tid + p * 256;
            int g = idx >> 9, rem = idx & 511, r = rem >> 3, k4 = rem & 7;
            b_lds[g][k4 * 4 + 0][r] = bbuf[p].x;
            b_lds[g][k4 * 4 + 1][r] = bbuf[p].y;
            b_lds[g][k4 * 4 + 2][r] = bbuf[p].z;
            b_lds[g][k4 * 4 + 3][r] = bbuf[p].w;
        }
    };

    load_t(0); store_t(); __syncthreads();
    for (int c = 0; c < 8; ++c) {
        if (c < 7) load_t((c + 1) * 32);  // reg double-buffer: hide global latency
        #pragma unroll 8
        for (int k = 0; k < 32; ++k) {
            float4 a4 = *(const float4*)&a_lds[k][tn * 4];
            float av[4] = {a4.x, a4.y, a4.z, a4.w};
            #pragma unroll
            for (int g = 0; g < 4; ++g) {
                float4 b4 = *(const float4*)&b_lds[g][k][th * 4];
                float bv[4] = {b4.x, b4.y, b4.z, b4.w};
                #pragma unroll
                for (int hi = 0; hi < 4; ++hi)
                    #pragma unroll
                    for (int ni = 0; ni < 4; ++ni)
                        acc[g][hi][ni] += bv[hi] * av[ni];
            }
        }
        __syncthreads();
        if (c < 7) { store_t(); __syncthreads(); }
    }

    const int colb = j0 + th * 4;
    if (mode != 1) {
        float4 bs[4];
        #pragma unroll
        for (int g = 0; g < 4; ++g) bs[g] = *(const float4*)&bias[g * 256 + colb];
        #pragma unroll
        for (int ni = 0; ni < 4; ++ni) {
            int row = m0 + tn * 4 + ni;
            if (row < M) {
                #pragma unroll
                for (int g = 0; g < 4; ++g) {
                    float4 o;
                    o.x = acc[g][0][ni] + bs[g].x;
                    o.y = acc[g][1][ni] + bs[g].y;
                    o.z = acc[g][2][ni] + bs[g].z;
                    o.w = acc[g][3][ni] + bs[g].w;
                    *(float4*)&Cout[row * 1024 + g * 256 + colb] = o;
                }
            }
        }
    } else {
        #pragma unroll
        for (int ni = 0; ni < 4; ++ni) {
            int n = m0 + tn * 4 + ni;
            int v = tok[n * 16 + t];
            const float* e = emb2 + v * 1024 + colb;
            float4 e0 = *(const float4*)(e);
            float4 e1 = *(const float4*)(e + 256);
            float4 e2 = *(const float4*)(e + 512);
            float4 e3 = *(const float4*)(e + 768);
            float4 co = *(const float4*)&cbuf[n * 256 + colb];
            float eg[4][4] = {{e0.x, e0.y, e0.z, e0.w}, {e1.x, e1.y, e1.z, e1.w},
                              {e2.x, e2.y, e2.z, e2.w}, {e3.x, e3.y, e3.z, e3.w}};
            float cold[4] = {co.x, co.y, co.z, co.w};
            float cn[4], hn[4];
            #pragma unroll
            for (int hi = 0; hi < 4; ++hi) {
                float ig = acc[0][hi][ni] + eg[0][hi];
                float fg = acc[1][hi][ni] + eg[1][hi];
                float gg = acc[2][hi][ni] + eg[2][hi];
                float og = acc[3][hi][ni] + eg[3][hi];
                float cc = sig_(fg) * cold[hi] + sig_(ig) * th_(gg);
                cn[hi] = cc;
                hn[hi] = sig_(og) * th_(cc);
            }
            float4 c4 = make_float4(cn[0], cn[1], cn[2], cn[3]);
            float4 h4 = make_float4(hn[0], hn[1], hn[2], hn[3]);
            *(float4*)&cbuf[n * 256 + colb] = c4;
            *(float4*)&hout[n * 256 + colb] = h4;
            if (lengths[n] == t + 1) *(float4*)&feats[n * 256 + colb] = h4;
        }
    }
}

// ---------------------------------------------------------------------------
// Token-LSTM step 0 (h0 = c0 = 0 -> pure pointwise from emb2 gather)
// ---------------------------------------------------------------------------
__global__ __launch_bounds__(256)
void step0_kernel(const int* __restrict__ tok, const int* __restrict__ lengths,
                  const float* __restrict__ emb2, float* __restrict__ cbuf,
                  float* __restrict__ h0, float* __restrict__ feats)
{
    int n = blockIdx.x, j = threadIdx.x;
    int v = tok[n * 16];
    const float* e = emb2 + v * 1024;
    float ig = e[j], gg = e[512 + j], og = e[768 + j];
    float c = sig_(ig) * th_(gg);          // f-gate * c0 drops (c0 = 0)
    float h = sig_(og) * th_(c);
    cbuf[n * 256 + j] = c;
    h0[n * 256 + j] = h;
    if (lengths[n] == 1) feats[n * 256 + j] = h;
}

// ---------------------------------------------------------------------------
// Instruction-LSTM scan: 4096 sequential steps, batch 1, H=256.
// 16 persistent blocks; block b owns h-indices [b*16, b*16+16). Its 64 W_hh
// rows live entirely in REGISTERS (float4 w_reg[16] per thread = the exact
// 64-float slice that thread's dot product needs) -> zero LDS traffic for W.
// Cross-block exchange: per-step hsbuf[s][256] pre-set to 0xFFFFFFFF (-NaN;
// h = sig*tanh is never NaN). Producers store their 16 words once (relaxed,
// agent scope); consumers poll their own word until != NaN. Single-write
// words mean any non-NaN value IS the final value: no fences, no flags,
// one coherence-point round trip per step.
// ---------------------------------------------------------------------------
__global__ __launch_bounds__(256, 1)
void scan_kernel(const float* __restrict__ gatesB, const float* __restrict__ Whh,
                 const float* __restrict__ linW, const float* __restrict__ linb,
                 float* __restrict__ hsbuf, float* __restrict__ out)
{
    const int b = blockIdx.x;
    const int tid = threadIdx.x;
    const int r = tid >> 2;               // 0..63: gate g = r>>4, row i = r&15
    const int q = tid & 3;                // k-quarter (64 floats each)
    const int g = r >> 4, i = r & 15;

    __shared__ float h_lds[256];
    __shared__ float gate_lds[64];
    __shared__ float red_lds[4];

    // W slice -> registers: row g*256 + b*16 + i, cols q*64 .. q*64+63
    float4 w_reg[16];
    {
        const float* wp = Whh + (g * 256 + b * 16 + i) * 256 + q * 64;
        #pragma unroll
        for (int kk = 0; kk < 16; ++kk) w_reg[kk] = *(const float4*)&wp[kk * 4];
    }
    h_lds[tid] = 0.f;                     // h_0 = 0
    float c_reg = 0.f;                    // c for row tid (lanes tid<16 only)
    const bool mine = (tid >> 4) == b;    // h word tid produced by own block
    __syncthreads();

    for (int s = 0; s < 4096; ++s) {
        // prefetch this step's input-gate row (independent of h -> overlaps)
        float bg0 = 0.f, bg1 = 0.f, bg2 = 0.f, bg3 = 0.f;
        if (tid < 16) {
            const float* gp = gatesB + s * 1024 + b * 16 + tid;
            bg0 = gp[0]; bg1 = gp[256]; bg2 = gp[512]; bg3 = gp[768];
        }
        // matvec: thread (r,q) covers k = q*64 .. q*64+63, W from registers
        float4 ac = make_float4(0.f, 0.f, 0.f, 0.f);
        #pragma unroll
        for (int kk = 0; kk < 16; ++kk) {
            float4 h4 = *(const float4*)&h_lds[q * 64 + kk * 4];
            ac.x += w_reg[kk].x * h4.x;
            ac.y += w_reg[kk].y * h4.y;
            ac.z += w_reg[kk].z * h4.z;
            ac.w += w_reg[kk].w * h4.w;
        }
        float sum = (ac.x + ac.y) + (ac.z + ac.w);
        sum += __shfl_xor(sum, 1);
        sum += __shfl_xor(sum, 2);
        if (q == 0) gate_lds[r] = sum;
        __syncthreads();
        if (tid < 16) {
            float ig = gate_lds[tid]      + bg0;
            float fg = gate_lds[16 + tid] + bg1;
            float gg = gate_lds[32 + tid] + bg2;
            float og = gate_lds[48 + tid] + bg3;
            float cc = sig_(fg) * c_reg + sig_(ig) * th_(gg);
            c_reg = cc;
            float hh = sig_(og) * th_(cc);
            h_lds[b * 16 + tid] = hh;     // local fast path for own words
            __hip_atomic_store(&hsbuf[(s + 1) * 256 + b * 16 + tid], hh,
                               __ATOMIC_RELAXED, __HIP_MEMORY_SCOPE_AGENT);
        }
        if (!mine) {
            const unsigned* p = (const unsigned*)&hsbuf[(s + 1) * 256 + tid];
            unsigned u = __hip_atomic_load(p, __ATOMIC_RELAXED,
                                           __HIP_MEMORY_SCOPE_AGENT);
            while (u == 0xFFFFFFFFu) {
                __builtin_amdgcn_s_sleep(1);
                u = __hip_atomic_load(p, __ATOMIC_RELAXED,
                                      __HIP_MEMORY_SCOPE_AGENT);
            }
            h_lds[tid] = __uint_as_float(u);
        }
        __syncthreads();
    }

    if (b == 0) {                         // out = h_T . lin_W + lin_b
        float p = h_lds[tid] * linW[tid];
        #pragma unroll
        for (int off = 1; off < 64; off <<= 1) p += __shfl_xor(p, off);
        if ((tid & 63) == 0) red_lds[tid >> 6] = p;
        __syncthreads();
        if (tid == 0) out[0] = red_lds[0] + red_lds[1] + red_lds[2] + red_lds[3] + linb[0];
    }
}

extern "C" void kernel_launch(void* const* d_in, const int* in_sizes, int n_in,
                              void* d_out, int out_size, void* d_ws, size_t ws_size,
                              hipStream_t stream)
{
    const int*   tok  = (const int*)d_in[0];
    const int*   len  = (const int*)d_in[1];
    const float* emb  = (const float*)d_in[2];
    const float* tWih = (const float*)d_in[3];
    const float* tWhh = (const float*)d_in[4];
    const float* tb   = (const float*)d_in[5];
    const float* iWih = (const float*)d_in[6];
    const float* iWhh = (const float*)d_in[7];
    const float* ib   = (const float*)d_in[8];
    const float* lW   = (const float*)d_in[9];
    const float* lb   = (const float*)d_in[10];
    float* out = (float*)d_out;

    // workspace layout (floats): ~44 MiB total
    float* emb2   = (float*)d_ws;           // [2000][1024]
    float* hbuf0  = emb2  + 2048000;        // [4096][256] ping
    float* hbuf1  = hbuf0 + 1048576;        // [4096][256] pong
    float* cbuf   = hbuf1 + 1048576;        // [4096][256]
    float* feats  = cbuf  + 1048576;        // [4096][256]
    float* gatesB = feats + 1048576;        // [4096][1024]
    float* hsbuf  = gatesB + 4194304;       // [4097][256] data-as-flag buffer

    // sentinel init: 0xFF bytes -> 0xFFFFFFFF (-NaN) in every hsbuf word
    hipMemsetAsync(hsbuf, 0xFF, (size_t)4097 * 256 * sizeof(float), stream);

    // emb2 = emb @ tok_W_ih^T + tok_b  (V=2000 rows)
    gemm_fused<<<dim3(32, 4), 256, 0, stream>>>(emb, tWih, tb, emb2, 2000, 0,
                                                nullptr, 0, nullptr, nullptr,
                                                nullptr, nullptr, nullptr);
    // token LSTM step 0 (pointwise)
    step0_kernel<<<4096, 256, 0, stream>>>(tok, len, emb2, cbuf, hbuf0, feats);
    // token LSTM steps 1..15 (fused GEMM + gather + activations)
    for (int t = 1; t < 16; ++t) {
        float* hprev = (t & 1) ? hbuf0 : hbuf1;
        float* hcur  = (t & 1) ? hbuf1 : hbuf0;
        gemm_fused<<<dim3(64, 4), 256, 0, stream>>>(hprev, tWhh, nullptr, nullptr,
                                                    4096, 1, tok, t, emb2, len,
                                                    cbuf, hcur, feats);
    }
    // gatesB = instr_feats @ ins_W_ih^T + ins_b
    gemm_fused<<<dim3(64, 4), 256, 0, stream>>>(feats, iWih, ib, gatesB, 4096, 2,
                                                nullptr, 0, nullptr, nullptr,
                                                nullptr, nullptr, nullptr);
    // 4096-step sequential instruction LSTM + final linear
    scan_kernel<<<NB, 256, 0, stream>>>(gatesB, iWhh, lW, lb, hsbuf, out);
}